// Round 14
// baseline (1033.843 us; speedup 1.0000x reference)
//
#include <hip/hip_runtime.h>

#define NN 20000   // nodes per graph
#define ER 320000  // raw edges
#define ET 340000  // edges incl. self-loops
#define CC 256     // H*D
#define HH 8
#define DD 32

// ---------------- utility ----------------

__global__ void zero_k(int* cnt, float* pooled) {
  int t = blockIdx.x * 256 + threadIdx.x;
  if (t < NN) cnt[t] = 0;
  if (pooled && t < 2 * CC) pooled[t] = 0.f;
}

// ---------------- CSR build ----------------

__global__ void hist_k(const int* __restrict__ ei, int* __restrict__ cnt) {
  int e = blockIdx.x * 256 + threadIdx.x;
  if (e >= ET) return;
  int dst = (e < ER) ? ei[ER + e] : (e - ER);
  atomicAdd(&cnt[dst], 1);
}

__global__ __launch_bounds__(1024) void scan_k(const int* __restrict__ cnt,
                                               int* __restrict__ offs,
                                               int* __restrict__ cur) {
  __shared__ int part[1024];
  int t = threadIdx.x;
  const int CH = (NN + 1023) / 1024;  // 20
  int b = t * CH; if (b > NN) b = NN;
  int e = b + CH; if (e > NN) e = NN;
  int s = 0;
  for (int i = b; i < e; ++i) s += cnt[i];
  part[t] = s;
  __syncthreads();
  for (int off = 1; off < 1024; off <<= 1) {
    int v = (t >= off) ? part[t - off] : 0;
    __syncthreads();
    part[t] += v;
    __syncthreads();
  }
  int run = (t > 0) ? part[t - 1] : 0;
  for (int i = b; i < e; ++i) {
    int c = cnt[i];
    offs[i] = run;
    cur[i] = run;
    run += c;
  }
  if (t == 0) offs[NN] = ET;
}

__global__ void scatter_k(const int* __restrict__ ei, int* __restrict__ cur,
                          int* __restrict__ csr_src, int* __restrict__ csr_dst) {
  int e = blockIdx.x * 256 + threadIdx.x;
  if (e >= ET) return;
  int src, dst;
  if (e < ER) { src = ei[e]; dst = ei[ER + e]; }
  else        { src = dst = e - ER; }
  int pos = atomicAdd(&cur[dst], 1);
  csr_src[pos] = src;
  csr_dst[pos] = dst;
}

// ---------------- GEMM: O[N,256] = X[N,K] @ W[K,256] ----------------
// r13 was LDS-instruction-bound: 4x4 microtile = 32 ds_read_b128/wave/k-step,
// 4 waves/block on one LDS pipe -> ~1536 cyc/k-step -> measured 49 us.
// This version: 64-thread (1-wave) blocks, 8x8 microtile, same 64x64 tile and
// 1252-block grid (all resident). 4 reads per 64 FMA -> ~2x fewer LDS cycles.
// a/b reads are 8-address broadcasts (conflict-free); A-writes consecutive
// dwords (free); Bs padded to 72. VGPR ~125 (no launch_bounds cap - r7).
__global__ __launch_bounds__(64) void gemm_k(const float* __restrict__ X,
                                             const float* __restrict__ W,
                                             float* __restrict__ O, int K) {
  __shared__ float As[2][16][68];  // [buf][kk][row]
  __shared__ float Bs[2][16][72];  // [buf][kk][col]
  int tid = threadIdx.x;
  int tx = tid & 7;    // 8 col-groups of 8
  int ty = tid >> 3;   // 8 row-groups of 8
  int rb = blockIdx.y * 64, cb = blockIdx.x * 64;

  // staging geometry: A: thread -> its row (64 rows), 16 kk (4 float4)
  //                   B: thread -> kk = tid>>2, cols (tid&3)*16 .. +15
  int gr = rb + tid; if (gr >= NN) gr = NN - 1;
  int bkk = tid >> 2;
  int bcol = (tid & 3) * 16;

  float acc[8][8] = {};
  float4 ar0, ar1, ar2, ar3, br0, br1, br2, br3;
  int nk = K >> 4;

#define GLOAD(k0)                                                       \
  do {                                                                  \
    const float* xp = &X[(size_t)gr * K + (k0)];                        \
    ar0 = *(const float4*)&xp[0];                                       \
    ar1 = *(const float4*)&xp[4];                                       \
    ar2 = *(const float4*)&xp[8];                                       \
    ar3 = *(const float4*)&xp[12];                                      \
    const float* wp = &W[(size_t)((k0) + bkk) * CC + cb + bcol];        \
    br0 = *(const float4*)&wp[0];                                       \
    br1 = *(const float4*)&wp[4];                                       \
    br2 = *(const float4*)&wp[8];                                       \
    br3 = *(const float4*)&wp[12];                                      \
  } while (0)

#define LWRITE(buf)                                                     \
  do {                                                                  \
    As[buf][0][tid] = ar0.x;  As[buf][1][tid] = ar0.y;                  \
    As[buf][2][tid] = ar0.z;  As[buf][3][tid] = ar0.w;                  \
    As[buf][4][tid] = ar1.x;  As[buf][5][tid] = ar1.y;                  \
    As[buf][6][tid] = ar1.z;  As[buf][7][tid] = ar1.w;                  \
    As[buf][8][tid] = ar2.x;  As[buf][9][tid] = ar2.y;                  \
    As[buf][10][tid] = ar2.z; As[buf][11][tid] = ar2.w;                 \
    As[buf][12][tid] = ar3.x; As[buf][13][tid] = ar3.y;                 \
    As[buf][14][tid] = ar3.z; As[buf][15][tid] = ar3.w;                 \
    *(float4*)&Bs[buf][bkk][bcol] = br0;                                \
    *(float4*)&Bs[buf][bkk][bcol + 4] = br1;                            \
    *(float4*)&Bs[buf][bkk][bcol + 8] = br2;                            \
    *(float4*)&Bs[buf][bkk][bcol + 12] = br3;                           \
  } while (0)

  GLOAD(0);
  LWRITE(0);
  __syncthreads();
  int cur = 0;
  for (int t = 0; t < nk; ++t) {
    if (t + 1 < nk) GLOAD((t + 1) << 4);
#pragma unroll
    for (int kk = 0; kk < 16; ++kk) {
      float a[8], b[8];
      *(float4*)&a[0] = *(const float4*)&As[cur][kk][ty * 8];
      *(float4*)&a[4] = *(const float4*)&As[cur][kk][ty * 8 + 4];
      *(float4*)&b[0] = *(const float4*)&Bs[cur][kk][tx * 8];
      *(float4*)&b[4] = *(const float4*)&Bs[cur][kk][tx * 8 + 4];
#pragma unroll
      for (int i = 0; i < 8; ++i)
#pragma unroll
        for (int j = 0; j < 8; ++j)
          acc[i][j] += a[i] * b[j];
    }
    if (t + 1 < nk) LWRITE(cur ^ 1);
    __syncthreads();
    cur ^= 1;
  }
#undef GLOAD
#undef LWRITE

#pragma unroll
  for (int i = 0; i < 8; ++i) {
    int r = rb + ty * 8 + i;
    if (r < NN) {
      *(float4*)&O[(size_t)r * CC + cb + tx * 8] =
          make_float4(acc[i][0], acc[i][1], acc[i][2], acc[i][3]);
      *(float4*)&O[(size_t)r * CC + cb + tx * 8 + 4] =
          make_float4(acc[i][4], acc[i][5], acc[i][6], acc[i][7]);
    }
  }
}

// ---------------- attention scores per (node, head) ----------------
__global__ void scores_k(const float* __restrict__ xw, const float* __restrict__ a_s,
                         const float* __restrict__ a_d, float* __restrict__ scs,
                         float* __restrict__ scd) {
  int t = blockIdx.x * blockDim.x + threadIdx.x;  // n*8+h
  if (t >= NN * HH) return;
  int h = t & 7, n = t >> 3;
  const float* row = xw + (size_t)n * CC + h * DD;
  const float* as = a_s + h * DD;
  const float* ad = a_d + h * DD;
  float ss = 0.f, sd = 0.f;
#pragma unroll
  for (int d = 0; d < DD; ++d) {
    float v = row[d];
    ss += v * as[d];
    sd += v * ad[d];
  }
  scs[t] = ss;
  scd[t] = sd;
}

// ---------------- per-CSR-slot leaky-relu'd raw attention ----------------
__global__ void alpha_k(const int* __restrict__ csr_src, const int* __restrict__ csr_dst,
                        const float* __restrict__ scs, const float* __restrict__ scd,
                        float* __restrict__ alpha) {
  int p = blockIdx.x * 256 + threadIdx.x;
  if (p >= ET) return;
  int s = csr_src[p], d = csr_dst[p];
  const float4* s4 = (const float4*)(scs + (size_t)s * 8);
  const float4* d4 = (const float4*)(scd + (size_t)d * 8);
  float4 a0 = s4[0], a1 = s4[1];
  float4 b0 = d4[0], b1 = d4[1];
  float4 r0, r1;
  float v;
  v = a0.x + b0.x; r0.x = v > 0.f ? v : 0.2f * v;
  v = a0.y + b0.y; r0.y = v > 0.f ? v : 0.2f * v;
  v = a0.z + b0.z; r0.z = v > 0.f ? v : 0.2f * v;
  v = a0.w + b0.w; r0.w = v > 0.f ? v : 0.2f * v;
  v = a1.x + b1.x; r1.x = v > 0.f ? v : 0.2f * v;
  v = a1.y + b1.y; r1.y = v > 0.f ? v : 0.2f * v;
  v = a1.z + b1.z; r1.z = v > 0.f ? v : 0.2f * v;
  v = a1.w + b1.w; r1.w = v > 0.f ? v : 0.2f * v;
  float4* o4 = (float4*)(alpha + (size_t)p * 8);
  o4[0] = r0; o4[1] = r1;
}

// ---------------- per-(node,head) softmax stats: m and 1/sum ----------------
__global__ __launch_bounds__(256) void stats_k(const float* __restrict__ alpha,
                                               const int* __restrict__ offs,
                                               float* __restrict__ ms,
                                               float* __restrict__ inv) {
  int wid = (blockIdx.x * 256 + threadIdx.x) >> 6;  // node
  if (wid >= NN) return;
  int lane = threadIdx.x & 63;
  int j = lane >> 3, h = lane & 7;
  int beg = offs[wid], end = offs[wid + 1];
  float m = -1e30f;
  for (int p = beg + j; p < end; p += 8)
    m = fmaxf(m, alpha[(size_t)p * 8 + h]);
#pragma unroll
  for (int off = 8; off <= 32; off <<= 1)
    m = fmaxf(m, __shfl_xor(m, off, 64));
  float s = 0.f;
  for (int p = beg + j; p < end; p += 8)
    s += __expf(alpha[(size_t)p * 8 + h] - m);
#pragma unroll
  for (int off = 8; off <= 32; off <<= 1)
    s += __shfl_xor(s, off, 64);
  if (lane < 8) {
    ms[(size_t)wid * 8 + h] = m;
    inv[(size_t)wid * 8 + h] = 1.f / s;
  }
}

// ---------------- weighted aggregate + bias + relu ----------------
// Softmax weight computed inline: per block (dst node), m and 1/s are
// CONSTANT per head -> load once, w = exp(a-m)*inv.
__global__ __launch_bounds__(256) void aggr_k(const float* __restrict__ xw,
                                              const float* __restrict__ alpha,
                                              const float* __restrict__ ms,
                                              const float* __restrict__ inv,
                                              const int* __restrict__ csr,
                                              const int* __restrict__ offs,
                                              const float* __restrict__ bias,
                                              float* __restrict__ out) {
  int n = blockIdx.x;
  int tid = threadIdx.x;
  int h = tid >> 5;
  int beg = offs[n], end = offs[n + 1];
  float m = ms[(size_t)n * 8 + h];
  float iv = inv[(size_t)n * 8 + h];
  float acc = 0.f;
  int p = beg;
  for (; p + 8 <= end; p += 8) {
    int s[8]; float wv[8]; float x[8];
#pragma unroll
    for (int i = 0; i < 8; ++i) s[i] = csr[p + i];
#pragma unroll
    for (int i = 0; i < 8; ++i) wv[i] = alpha[(size_t)(p + i) * 8 + h];
#pragma unroll
    for (int i = 0; i < 8; ++i) x[i] = xw[(size_t)s[i] * CC + tid];
#pragma unroll
    for (int i = 0; i < 8; ++i) acc += __expf(wv[i] - m) * iv * x[i];
  }
  for (; p + 4 <= end; p += 4) {
    int s[4]; float wv[4]; float x[4];
#pragma unroll
    for (int i = 0; i < 4; ++i) s[i] = csr[p + i];
#pragma unroll
    for (int i = 0; i < 4; ++i) wv[i] = alpha[(size_t)(p + i) * 8 + h];
#pragma unroll
    for (int i = 0; i < 4; ++i) x[i] = xw[(size_t)s[i] * CC + tid];
#pragma unroll
    for (int i = 0; i < 4; ++i) acc += __expf(wv[i] - m) * iv * x[i];
  }
  for (; p < end; ++p)
    acc += __expf(alpha[(size_t)p * 8 + h] - m) * iv * xw[(size_t)csr[p] * CC + tid];
  float r = acc + bias[tid];
  out[(size_t)n * CC + tid] = (r > 0.f) ? r : 0.f;
}

// ---------------- mean pool ----------------
__global__ void pool_k(const float* __restrict__ x, float* __restrict__ pooled) {
  int tid = threadIdx.x;
  int rb = blockIdx.x * 50;
  float acc = 0.f;
  for (int r = 0; r < 50; ++r) acc += x[(size_t)(rb + r) * CC + tid];
  atomicAdd(&pooled[tid], acc * (1.f / NN));
}

// ---------------- head GEMVs: one wave per output element ----------------
// y[o] = b[o&255] + dot(x + (o>>8)*256, W + (o&255)*256), o in [0,512)
__global__ __launch_bounds__(256) void head12_k(const float* __restrict__ x,
                                                const float* __restrict__ W,
                                                const float* __restrict__ b,
                                                float* __restrict__ y) {
  int o = (blockIdx.x * 256 + threadIdx.x) >> 6;
  if (o >= 512) return;
  int lane = threadIdx.x & 63;
  int g = o >> 8, t = o & 255;
  float4 wv = *(const float4*)&W[(size_t)t * 256 + lane * 4];
  float4 xv = *(const float4*)&x[g * 256 + lane * 4];
  float s = wv.x * xv.x + wv.y * xv.y + wv.z * xv.z + wv.w * xv.w;
#pragma unroll
  for (int off = 32; off >= 1; off >>= 1) s += __shfl_xor(s, off, 64);
  if (lane == 0) y[o] = s + b[t];
}

// out[o] = b[o] + dot(f[0..512], W + o*512), o in [0,256)
__global__ __launch_bounds__(256) void head3_k(const float* __restrict__ f,
                                               const float* __restrict__ W,
                                               const float* __restrict__ b,
                                               float* __restrict__ out) {
  int o = (blockIdx.x * 256 + threadIdx.x) >> 6;
  if (o >= 256) return;
  int lane = threadIdx.x & 63;
  const float* wr = W + (size_t)o * 512;
  float4 w0 = *(const float4*)&wr[lane * 4];
  float4 w1 = *(const float4*)&wr[lane * 4 + 256];
  float4 f0 = *(const float4*)&f[lane * 4];
  float4 f1 = *(const float4*)&f[lane * 4 + 256];
  float s = w0.x * f0.x + w0.y * f0.y + w0.z * f0.z + w0.w * f0.w +
            w1.x * f1.x + w1.y * f1.y + w1.z * f1.z + w1.w * f1.w;
#pragma unroll
  for (int off = 32; off >= 1; off >>= 1) s += __shfl_xor(s, off, 64);
  if (lane == 0) out[o] = s + b[o];
}

// ---------------- launch ----------------
extern "C" void kernel_launch(void* const* d_in, const int* in_sizes, int n_in,
                              void* d_out, int out_size, void* d_ws, size_t ws_size,
                              hipStream_t stream) {
  const float* cfg_x = (const float*)d_in[0];
  const float* dfg_x = (const float*)d_in[1];
  const int* cfg_ei = (const int*)d_in[2];
  const int* dfg_ei = (const int*)d_in[3];
  const float *lin[2][3], *as_[2][3], *ad_[2][3], *bs_[2][3];
  for (int g = 0; g < 2; ++g)
    for (int i = 0; i < 3; ++i) {
      int base = 4 + g * 12 + i * 4;
      lin[g][i] = (const float*)d_in[base];
      as_[g][i] = (const float*)d_in[base + 1];
      ad_[g][i] = (const float*)d_in[base + 2];
      bs_[g][i] = (const float*)d_in[base + 3];
    }
  const float* mha_in_w = (const float*)d_in[28];
  const float* mha_in_b = (const float*)d_in[29];
  const float* mha_out_w = (const float*)d_in[30];
  const float* mha_out_b = (const float*)d_in[31];
  const float* fus_w = (const float*)d_in[32];
  const float* fus_b = (const float*)d_in[33];
  float* outp = (float*)d_out;

  char* w = (char*)d_ws;
  size_t o = 0;
  auto alloc = [&](size_t bytes) -> char* {
    char* p = w + o;
    o += (bytes + 255) & ~(size_t)255;
    return p;
  };
  float* bufA = (float*)alloc((size_t)NN * CC * 4);
  float* bufB = (float*)alloc((size_t)NN * CC * 4);
  float* scs = (float*)alloc((size_t)NN * HH * 4);
  float* scd = (float*)alloc((size_t)NN * HH * 4);
  float* ms = (float*)alloc((size_t)NN * HH * 4);
  float* inv = (float*)alloc((size_t)NN * HH * 4);
  float* alpha = (float*)alloc((size_t)ET * HH * 4);
  int* csr = (int*)alloc((size_t)ET * 4);
  int* csrd = (int*)alloc((size_t)ET * 4);
  int* offs = (int*)alloc((size_t)(NN + 1) * 4);
  int* cnt = (int*)alloc((size_t)NN * 4);
  int* cur = (int*)alloc((size_t)NN * 4);
  float* pooled = (float*)alloc(2 * CC * 4);
  float* vbuf = (float*)alloc(2 * CC * 4);
  float* fbuf = (float*)alloc(2 * CC * 4);

  const int* ei[2] = {cfg_ei, dfg_ei};
  const float* xin[2] = {cfg_x, dfg_x};
  const int K0[2] = {64, 32};

  for (int g = 0; g < 2; ++g) {
    zero_k<<<(NN + 255) / 256, 256, 0, stream>>>(cnt, g == 0 ? pooled : nullptr);
    hist_k<<<(ET + 255) / 256, 256, 0, stream>>>(ei[g], cnt);
    scan_k<<<1, 1024, 0, stream>>>(cnt, offs, cur);
    scatter_k<<<(ET + 255) / 256, 256, 0, stream>>>(ei[g], cur, csr, csrd);

    const float* x = xin[g];
    for (int l = 0; l < 3; ++l) {
      int K = (l == 0) ? K0[g] : CC;
      dim3 grid(CC / 64, (NN + 63) / 64);
      gemm_k<<<grid, 64, 0, stream>>>(x, lin[g][l], bufA, K);
      scores_k<<<(NN * HH + 255) / 256, 256, 0, stream>>>(bufA, as_[g][l], ad_[g][l],
                                                          scs, scd);
      alpha_k<<<(ET + 255) / 256, 256, 0, stream>>>(csr, csrd, scs, scd, alpha);
      stats_k<<<(NN * 64 + 255) / 256, 256, 0, stream>>>(alpha, offs, ms, inv);
      aggr_k<<<NN, 256, 0, stream>>>(bufA, alpha, ms, inv, csr, offs, bs_[g][l], bufB);
      x = bufB;
    }
    pool_k<<<(NN / 50), 256, 0, stream>>>(bufB, pooled + g * CC);
  }
  head12_k<<<128, 256, 0, stream>>>(pooled, mha_in_w + 512 * 256, mha_in_b + 512, vbuf);
  head12_k<<<128, 256, 0, stream>>>(vbuf, mha_out_w, mha_out_b, fbuf);
  head3_k<<<64, 256, 0, stream>>>(fbuf, fus_w, fus_b, outp);
}

// Round 15
// 869.749 us; speedup vs baseline: 1.1887x; 1.1887x over previous
//
#include <hip/hip_runtime.h>

#define NN 20000   // nodes per graph
#define ER 320000  // raw edges
#define ET 340000  // edges incl. self-loops
#define CC 256     // H*D
#define HH 8
#define DD 32

// ---------------- utility ----------------

__global__ void zero_k(int* cnt, float* pooled) {
  int t = blockIdx.x * 256 + threadIdx.x;
  if (t < NN) cnt[t] = 0;
  if (pooled && t < 2 * CC) pooled[t] = 0.f;
}

// ---------------- CSR build ----------------

__global__ void hist_k(const int* __restrict__ ei, int* __restrict__ cnt) {
  int e = blockIdx.x * 256 + threadIdx.x;
  if (e >= ET) return;
  int dst = (e < ER) ? ei[ER + e] : (e - ER);
  atomicAdd(&cnt[dst], 1);
}

__global__ __launch_bounds__(1024) void scan_k(const int* __restrict__ cnt,
                                               int* __restrict__ offs,
                                               int* __restrict__ cur) {
  __shared__ int part[1024];
  int t = threadIdx.x;
  const int CH = (NN + 1023) / 1024;  // 20
  int b = t * CH; if (b > NN) b = NN;
  int e = b + CH; if (e > NN) e = NN;
  int s = 0;
  for (int i = b; i < e; ++i) s += cnt[i];
  part[t] = s;
  __syncthreads();
  for (int off = 1; off < 1024; off <<= 1) {
    int v = (t >= off) ? part[t - off] : 0;
    __syncthreads();
    part[t] += v;
    __syncthreads();
  }
  int run = (t > 0) ? part[t - 1] : 0;
  for (int i = b; i < e; ++i) {
    int c = cnt[i];
    offs[i] = run;
    cur[i] = run;
    run += c;
  }
  if (t == 0) offs[NN] = ET;
}

__global__ void scatter_k(const int* __restrict__ ei, int* __restrict__ cur,
                          int* __restrict__ csr_src) {
  int e = blockIdx.x * 256 + threadIdx.x;
  if (e >= ET) return;
  int src, dst;
  if (e < ER) { src = ei[e]; dst = ei[ER + e]; }
  else        { src = dst = e - ER; }
  int pos = atomicAdd(&cur[dst], 1);
  csr_src[pos] = src;
}

// ---------------- GEMM + fused attention-score epilogue ----------------
// r13's proven gemm (64x64 tile, 256 threads, 4x4 microtile, BK=16, dbuf,
// conflict-free staging, 1252 blocks -> ~20 waves/CU, measured 49.3 us /
// 0 bank conflicts). NOTE: no min-waves launch_bounds (r7: VGPR cap spills);
// 64-thread blocks regress 4x in wave count (r14).
// Epilogue: a 64-col tile = exactly heads 2bx,2bx+1, so this block computes
// scs/scd for those heads from in-register acc (kills scores_k pass).
__global__ __launch_bounds__(256) void gemm_k(const float* __restrict__ X,
                                              const float* __restrict__ W,
                                              float* __restrict__ O, int K,
                                              const float* __restrict__ a_s,
                                              const float* __restrict__ a_d,
                                              float* __restrict__ scs,
                                              float* __restrict__ scd) {
  __shared__ float As[2][16][68];  // [buf][kk][row]
  __shared__ float Bs[2][16][68];  // [buf][kk][col]
  int tid = threadIdx.x;
  int tx = tid & 15;   // 16 col-groups of 4
  int ty = tid >> 4;   // 16 row-groups of 4
  int rb = blockIdx.y * 64, cb = blockIdx.x * 64;

  // staging geometry (1 float4 of A + 1 float4 of B per thread)
  int arow = tid & 63;          // 64 distinct rows per wave -> conflict-free
  int akc = (tid >> 6) * 4;     // kk base 0,4,8,12 (wave-uniform)
  int bkk = tid >> 4;           // 0..15
  int bcol = (tid & 15) * 4;    // 0..60
  int gr = rb + arow; if (gr >= NN) gr = NN - 1;

  float acc[4][4] = {};
  float4 ar, br;
  int nk = K >> 4;

#define GLOAD(k0)                                                     \
  do {                                                                \
    ar = *(const float4*)&X[(size_t)gr * K + (k0) + akc];             \
    br = *(const float4*)&W[(size_t)((k0) + bkk) * CC + cb + bcol];   \
  } while (0)

#define LWRITE(buf)                                                   \
  do {                                                                \
    As[buf][akc][arow] = ar.x; As[buf][akc + 1][arow] = ar.y;         \
    As[buf][akc + 2][arow] = ar.z; As[buf][akc + 3][arow] = ar.w;     \
    *(float4*)&Bs[buf][bkk][bcol] = br;                               \
  } while (0)

  GLOAD(0);
  LWRITE(0);
  __syncthreads();
  int cur = 0;
  for (int t = 0; t < nk; ++t) {
    if (t + 1 < nk) GLOAD((t + 1) << 4);
#pragma unroll
    for (int kk = 0; kk < 16; ++kk) {
      float4 a = *(const float4*)&As[cur][kk][ty * 4];
      float4 b = *(const float4*)&Bs[cur][kk][tx * 4];
      acc[0][0] += a.x * b.x; acc[0][1] += a.x * b.y; acc[0][2] += a.x * b.z; acc[0][3] += a.x * b.w;
      acc[1][0] += a.y * b.x; acc[1][1] += a.y * b.y; acc[1][2] += a.y * b.z; acc[1][3] += a.y * b.w;
      acc[2][0] += a.z * b.x; acc[2][1] += a.z * b.y; acc[2][2] += a.z * b.z; acc[2][3] += a.z * b.w;
      acc[3][0] += a.w * b.x; acc[3][1] += a.w * b.y; acc[3][2] += a.w * b.z; acc[3][3] += a.w * b.w;
    }
    if (t + 1 < nk) LWRITE(cur ^ 1);
    __syncthreads();
    cur ^= 1;
  }
#undef GLOAD
#undef LWRITE

#pragma unroll
  for (int i = 0; i < 4; ++i) {
    int r = rb + ty * 4 + i;
    if (r < NN) {
      *(float4*)&O[(size_t)r * CC + cb + tx * 4] =
          make_float4(acc[i][0], acc[i][1], acc[i][2], acc[i][3]);
    }
  }

  // fused per-row attention-score partials (heads 2bx and 2bx+1)
  {
    int h = 2 * blockIdx.x + (tx >> 3);
    int dbase = (tx & 7) * 4;
    const float* asp = a_s + h * DD + dbase;
    const float* adp = a_d + h * DD + dbase;
    float as0 = asp[0], as1 = asp[1], as2 = asp[2], as3 = asp[3];
    float ad0 = adp[0], ad1 = adp[1], ad2 = adp[2], ad3 = adp[3];
#pragma unroll
    for (int i = 0; i < 4; ++i) {
      float ps = acc[i][0] * as0 + acc[i][1] * as1 + acc[i][2] * as2 + acc[i][3] * as3;
      float pd = acc[i][0] * ad0 + acc[i][1] * ad1 + acc[i][2] * ad2 + acc[i][3] * ad3;
#pragma unroll
      for (int off = 1; off <= 4; off <<= 1) {
        ps += __shfl_xor(ps, off, 64);
        pd += __shfl_xor(pd, off, 64);
      }
      if ((tx & 7) == 0) {
        int r = rb + ty * 4 + i;
        if (r < NN) {
          scs[(size_t)r * 8 + h] = ps;
          scd[(size_t)r * 8 + h] = pd;
        }
      }
    }
  }
}

// ---------------- fused alpha + softmax stats ----------------
// One wave per node: lane = j*8+h. Computes leaky-relu'd alpha per CSR slot
// (gathering scs[src]), writes it, and produces per-(node,head) m and 1/sum.
__global__ __launch_bounds__(256) void stats_k(const float* __restrict__ scs,
                                               const float* __restrict__ scd,
                                               const int* __restrict__ csr,
                                               const int* __restrict__ offs,
                                               float* __restrict__ alpha,
                                               float* __restrict__ ms,
                                               float* __restrict__ inv) {
  int wid = (blockIdx.x * 256 + threadIdx.x) >> 6;  // node
  if (wid >= NN) return;
  int lane = threadIdx.x & 63;
  int j = lane >> 3, h = lane & 7;
  int beg = offs[wid], end = offs[wid + 1];
  float sd = scd[(size_t)wid * 8 + h];
  float m = -1e30f;
  for (int p = beg + j; p < end; p += 8) {
    int s = csr[p];
    float a = scs[(size_t)s * 8 + h] + sd;
    a = (a > 0.f) ? a : 0.2f * a;
    alpha[(size_t)p * 8 + h] = a;
    m = fmaxf(m, a);
  }
#pragma unroll
  for (int off = 8; off <= 32; off <<= 1)
    m = fmaxf(m, __shfl_xor(m, off, 64));
  float ssum = 0.f;
  for (int p = beg + j; p < end; p += 8)
    ssum += __expf(alpha[(size_t)p * 8 + h] - m);
#pragma unroll
  for (int off = 8; off <= 32; off <<= 1)
    ssum += __shfl_xor(ssum, off, 64);
  if (lane < 8) {
    ms[(size_t)wid * 8 + h] = m;
    inv[(size_t)wid * 8 + h] = 1.f / ssum;
  }
}

// ---------------- weighted aggregate + bias + relu ----------------
// Softmax weight computed inline: per block (dst node), m and 1/s are
// CONSTANT per head -> load once, w = exp(a-m)*inv.
__global__ __launch_bounds__(256) void aggr_k(const float* __restrict__ xw,
                                              const float* __restrict__ alpha,
                                              const float* __restrict__ ms,
                                              const float* __restrict__ inv,
                                              const int* __restrict__ csr,
                                              const int* __restrict__ offs,
                                              const float* __restrict__ bias,
                                              float* __restrict__ out) {
  int n = blockIdx.x;
  int tid = threadIdx.x;
  int h = tid >> 5;
  int beg = offs[n], end = offs[n + 1];
  float m = ms[(size_t)n * 8 + h];
  float iv = inv[(size_t)n * 8 + h];
  float acc = 0.f;
  int p = beg;
  for (; p + 8 <= end; p += 8) {
    int s[8]; float wv[8]; float x[8];
#pragma unroll
    for (int i = 0; i < 8; ++i) s[i] = csr[p + i];
#pragma unroll
    for (int i = 0; i < 8; ++i) wv[i] = alpha[(size_t)(p + i) * 8 + h];
#pragma unroll
    for (int i = 0; i < 8; ++i) x[i] = xw[(size_t)s[i] * CC + tid];
#pragma unroll
    for (int i = 0; i < 8; ++i) acc += __expf(wv[i] - m) * iv * x[i];
  }
  for (; p + 4 <= end; p += 4) {
    int s[4]; float wv[4]; float x[4];
#pragma unroll
    for (int i = 0; i < 4; ++i) s[i] = csr[p + i];
#pragma unroll
    for (int i = 0; i < 4; ++i) wv[i] = alpha[(size_t)(p + i) * 8 + h];
#pragma unroll
    for (int i = 0; i < 4; ++i) x[i] = xw[(size_t)s[i] * CC + tid];
#pragma unroll
    for (int i = 0; i < 4; ++i) acc += __expf(wv[i] - m) * iv * x[i];
  }
  for (; p < end; ++p)
    acc += __expf(alpha[(size_t)p * 8 + h] - m) * iv * xw[(size_t)csr[p] * CC + tid];
  float r = acc + bias[tid];
  out[(size_t)n * CC + tid] = (r > 0.f) ? r : 0.f;
}

// ---------------- mean pool ----------------
__global__ void pool_k(const float* __restrict__ x, float* __restrict__ pooled) {
  int tid = threadIdx.x;
  int rb = blockIdx.x * 50;
  float acc = 0.f;
  for (int r = 0; r < 50; ++r) acc += x[(size_t)(rb + r) * CC + tid];
  atomicAdd(&pooled[tid], acc * (1.f / NN));
}

// ---------------- head GEMVs: one wave per output element ----------------
// y[o] = b[o&255] + dot(x + (o>>8)*256, W + (o&255)*256), o in [0,512)
__global__ __launch_bounds__(256) void head12_k(const float* __restrict__ x,
                                                const float* __restrict__ W,
                                                const float* __restrict__ b,
                                                float* __restrict__ y) {
  int o = (blockIdx.x * 256 + threadIdx.x) >> 6;
  if (o >= 512) return;
  int lane = threadIdx.x & 63;
  int g = o >> 8, t = o & 255;
  float4 wv = *(const float4*)&W[(size_t)t * 256 + lane * 4];
  float4 xv = *(const float4*)&x[g * 256 + lane * 4];
  float s = wv.x * xv.x + wv.y * xv.y + wv.z * xv.z + wv.w * xv.w;
#pragma unroll
  for (int off = 32; off >= 1; off >>= 1) s += __shfl_xor(s, off, 64);
  if (lane == 0) y[o] = s + b[t];
}

// out[o] = b[o] + dot(f[0..512], W + o*512), o in [0,256)
__global__ __launch_bounds__(256) void head3_k(const float* __restrict__ f,
                                               const float* __restrict__ W,
                                               const float* __restrict__ b,
                                               float* __restrict__ out) {
  int o = (blockIdx.x * 256 + threadIdx.x) >> 6;
  if (o >= 256) return;
  int lane = threadIdx.x & 63;
  const float* wr = W + (size_t)o * 512;
  float4 w0 = *(const float4*)&wr[lane * 4];
  float4 w1 = *(const float4*)&wr[lane * 4 + 256];
  float4 f0 = *(const float4*)&f[lane * 4];
  float4 f1 = *(const float4*)&f[lane * 4 + 256];
  float s = w0.x * f0.x + w0.y * f0.y + w0.z * f0.z + w0.w * f0.w +
            w1.x * f1.x + w1.y * f1.y + w1.z * f1.z + w1.w * f1.w;
#pragma unroll
  for (int off = 32; off >= 1; off >>= 1) s += __shfl_xor(s, off, 64);
  if (lane == 0) out[o] = s + b[o];
}

// ---------------- launch ----------------
extern "C" void kernel_launch(void* const* d_in, const int* in_sizes, int n_in,
                              void* d_out, int out_size, void* d_ws, size_t ws_size,
                              hipStream_t stream) {
  const float* cfg_x = (const float*)d_in[0];
  const float* dfg_x = (const float*)d_in[1];
  const int* cfg_ei = (const int*)d_in[2];
  const int* dfg_ei = (const int*)d_in[3];
  const float *lin[2][3], *as_[2][3], *ad_[2][3], *bs_[2][3];
  for (int g = 0; g < 2; ++g)
    for (int i = 0; i < 3; ++i) {
      int base = 4 + g * 12 + i * 4;
      lin[g][i] = (const float*)d_in[base];
      as_[g][i] = (const float*)d_in[base + 1];
      ad_[g][i] = (const float*)d_in[base + 2];
      bs_[g][i] = (const float*)d_in[base + 3];
    }
  const float* mha_in_w = (const float*)d_in[28];
  const float* mha_in_b = (const float*)d_in[29];
  const float* mha_out_w = (const float*)d_in[30];
  const float* mha_out_b = (const float*)d_in[31];
  const float* fus_w = (const float*)d_in[32];
  const float* fus_b = (const float*)d_in[33];
  float* outp = (float*)d_out;

  char* w = (char*)d_ws;
  size_t o = 0;
  auto alloc = [&](size_t bytes) -> char* {
    char* p = w + o;
    o += (bytes + 255) & ~(size_t)255;
    return p;
  };
  float* bufA = (float*)alloc((size_t)NN * CC * 4);
  float* bufB = (float*)alloc((size_t)NN * CC * 4);
  float* scs = (float*)alloc((size_t)NN * HH * 4);
  float* scd = (float*)alloc((size_t)NN * HH * 4);
  float* ms = (float*)alloc((size_t)NN * HH * 4);
  float* inv = (float*)alloc((size_t)NN * HH * 4);
  float* alpha = (float*)alloc((size_t)ET * HH * 4);
  int* csr = (int*)alloc((size_t)ET * 4);
  int* offs = (int*)alloc((size_t)(NN + 1) * 4);
  int* cnt = (int*)alloc((size_t)NN * 4);
  int* cur = (int*)alloc((size_t)NN * 4);
  float* pooled = (float*)alloc(2 * CC * 4);
  float* vbuf = (float*)alloc(2 * CC * 4);
  float* fbuf = (float*)alloc(2 * CC * 4);

  const int* ei[2] = {cfg_ei, dfg_ei};
  const float* xin[2] = {cfg_x, dfg_x};
  const int K0[2] = {64, 32};

  for (int g = 0; g < 2; ++g) {
    zero_k<<<(NN + 255) / 256, 256, 0, stream>>>(cnt, g == 0 ? pooled : nullptr);
    hist_k<<<(ET + 255) / 256, 256, 0, stream>>>(ei[g], cnt);
    scan_k<<<1, 1024, 0, stream>>>(cnt, offs, cur);
    scatter_k<<<(ET + 255) / 256, 256, 0, stream>>>(ei[g], cur, csr);

    const float* x = xin[g];
    for (int l = 0; l < 3; ++l) {
      int K = (l == 0) ? K0[g] : CC;
      dim3 grid(CC / 64, (NN + 63) / 64);
      gemm_k<<<grid, 256, 0, stream>>>(x, lin[g][l], bufA, K,
                                       as_[g][l], ad_[g][l], scs, scd);
      stats_k<<<(NN * 64 + 255) / 256, 256, 0, stream>>>(scs, scd, csr, offs,
                                                         alpha, ms, inv);
      aggr_k<<<NN, 256, 0, stream>>>(bufA, alpha, ms, inv, csr, offs, bs_[g][l], bufB);
      x = bufB;
    }
    pool_k<<<(NN / 50), 256, 0, stream>>>(bufB, pooled + g * CC);
  }
  head12_k<<<128, 256, 0, stream>>>(pooled, mha_in_w + 512 * 256, mha_in_b + 512, vbuf);
  head12_k<<<128, 256, 0, stream>>>(vbuf, mha_out_w, mha_out_b, fbuf);
  head3_k<<<64, 256, 0, stream>>>(fbuf, fus_w, fus_b, outp);
}